// Round 12
// baseline (497.734 us; speedup 1.0000x reference)
//
#include <hip/hip_runtime.h>
#include <math.h>

typedef _Float16 f16;
typedef _Float16 f16x2 __attribute__((ext_vector_type(2)));
typedef _Float16 f16x4 __attribute__((ext_vector_type(4)));
typedef _Float16 f16x8 __attribute__((ext_vector_type(8)));
typedef __fp16 h16x2 __attribute__((ext_vector_type(2)));
typedef float f32x2 __attribute__((ext_vector_type(2)));
typedef float f32x4 __attribute__((ext_vector_type(4)));
typedef float f32x16 __attribute__((ext_vector_type(16)));

#define N_TOK 2048
#define C_DIM 1024
#define E_NUM 8
#define F_DIM 2048
#define BM 128

// ws layout (bytes)
#define WS_COUNTS    0
#define WS_OFFSETS   64
#define WS_CURSOR    192
#define WS_TOPI      256
#define WS_TOPW      (WS_TOPI + 16384)
#define WS_ROWS      (WS_TOPW + 16384)
#define WS_SLOT      (WS_ROWS + 16384)
#define WS_X16       (1ull << 20)     // 4 MB
#define WS_H         (6ull << 20)     // 16.8 MB
#define WS_Y0        (23ull << 20)    // 8.4 MB
#define WS_Y1        (32ull << 20)    // 8.4 MB

__device__ __forceinline__ void glds16(const void* g, void* l) {
  __builtin_amdgcn_global_load_lds((const __attribute__((address_space(1))) void*)g,
                                   (__attribute__((address_space(3))) void*)l, 16, 0, 0);
}

__device__ __forceinline__ f16x2 pkrtz(float a, float b) {
  union { h16x2 h; f16x2 f; } u;
  u.h = __builtin_amdgcn_cvt_pkrtz(a, b);
  return u.f;
}

__device__ __forceinline__ int f2i(f16x2 v) {
  union { f16x2 f; int i; } u; u.f = v; return u.i;
}

// ---------------- x fp32 -> fp16 ----------------
__global__ void cvtx_kernel(const float* __restrict__ x, f16* __restrict__ x16) {
  int i = (blockIdx.x * 256 + threadIdx.x) * 8;
  f32x4 a = *(const f32x4*)(x + i);
  f32x4 b = *(const f32x4*)(x + i + 4);
  union { f16x8 v; f16x2 h[4]; } u;
  u.h[0] = pkrtz(a[0], a[1]);
  u.h[1] = pkrtz(a[2], a[3]);
  u.h[2] = pkrtz(b[0], b[1]);
  u.h[3] = pkrtz(b[2], b[3]);
  *(f16x8*)(x16 + i) = u.v;
}

// ---------------- router ----------------
__global__ void router_kernel(const float* __restrict__ x, const float* __restrict__ Wr,
                              int* counts, int* topi, float* topw) {
  int tok = blockIdx.x * 4 + (threadIdx.x >> 6);
  int lane = threadIdx.x & 63;
  const float* xr = x + (size_t)tok * C_DIM;
  float xv[16];
#pragma unroll
  for (int i = 0; i < 16; ++i) xv[i] = xr[i * 64 + lane];
  float logit[E_NUM];
#pragma unroll
  for (int e = 0; e < E_NUM; ++e) {
    const float* wr = Wr + (size_t)e * C_DIM;
    float acc = 0.f;
#pragma unroll
    for (int i = 0; i < 16; ++i) acc += xv[i] * wr[i * 64 + lane];
#pragma unroll
    for (int s = 1; s < 64; s <<= 1) acc += __shfl_xor(acc, s, 64);
    logit[e] = acc;
  }
  if (lane == 0) {
    float m = logit[0];
#pragma unroll
    for (int e = 1; e < E_NUM; ++e) m = fmaxf(m, logit[e]);
    float p[E_NUM];
#pragma unroll
    for (int e = 0; e < E_NUM; ++e) p[e] = expf(logit[e] - m);
    float p0 = -1.f, p1 = -1.f;
    int i0 = 0, i1 = 0;
#pragma unroll
    for (int e = 0; e < E_NUM; ++e) {
      float v = p[e];
      if (v > p0) { p1 = p0; i1 = i0; p0 = v; i0 = e; }
      else if (v > p1) { p1 = v; i1 = e; }
    }
    float inv = 1.f / (p0 + p1);
    topi[2 * tok] = i0; topi[2 * tok + 1] = i1;
    topw[2 * tok] = p0 * inv; topw[2 * tok + 1] = p1 * inv;
    atomicAdd(&counts[i0], 1);
    atomicAdd(&counts[i1], 1);
  }
}

// ---------------- scan ----------------
__global__ void scan_kernel(const int* counts, int* offsets, int* cursor) {
  if (threadIdx.x == 0) {
    int o = 0;
    for (int e = 0; e < E_NUM; ++e) {
      offsets[e] = o; cursor[e] = o;
      o += counts[e];
    }
    offsets[E_NUM] = o;
  }
}

// ---------------- scatter ----------------
__global__ void scatter_kernel(const int* __restrict__ topi, int* cursor,
                               int* rows_perm, int* slot_of) {
  int n = blockIdx.x * blockDim.x + threadIdx.x;
  if (n >= N_TOK) return;
#pragma unroll
  for (int k = 0; k < 2; ++k) {
    int e = topi[2 * n + k];
    int pos = atomicAdd(&cursor[e], 1);
    rows_perm[pos] = n;
    slot_of[2 * n + k] = pos;
  }
}

#define ROT3(P0, P1, P2) { f16* _t = P0; P0 = P1; P1 = P2; P2 = _t; }

// ================= up-proj: h = silu(x@w1)*(x@w3) =================
// 128x64 tile, BK=32, 4 waves (wave 64x32), 32x32x16 MFMA, 4 blocks/CU.
// A: glds (swizzled src, 3-buf, depth-2). B: coalesced dwordx2 fp32 loads
// + pkrtz + shfl_xor(32) col-exchange -> thread-linear ds_write_b128.
// Thread t: col pair c0=2*(lane&31), k-window = 8*wid + 4*fh (4 rows).
#define UP_ISSUE(R1, R3, KN)                                              \
  { _Pragma("unroll") for (int j = 0; j < 4; ++j) {                       \
      R1[j] = *(const f32x2*)(w1p + (size_t)((KN) + j) * F_DIM);          \
      R3[j] = *(const f32x2*)(w3p + (size_t)((KN) + j) * F_DIM); }        \
    glds16(asrc[0] + (KN), a_f + (wid * 64) * 8);                         \
    glds16(asrc[1] + (KN), a_f + (256 + wid * 64) * 8); }

#define PACK1(R, DST)                                                     \
  { int a01 = f2i(pkrtz(R[0][0], R[1][0]));                               \
    int a23 = f2i(pkrtz(R[2][0], R[3][0]));                               \
    int b01 = f2i(pkrtz(R[0][1], R[1][1]));                               \
    int b23 = f2i(pkrtz(R[2][1], R[3][1]));                               \
    int x1 = fh ? a01 : b01;     /* send the col you don't own */         \
    int x2 = fh ? a23 : b23;                                              \
    int y1 = __shfl_xor(x1, 32, 64);                                      \
    int y2 = __shfl_xor(x2, 32, 64);                                      \
    union { f16x8 v; int d[4]; } u;                                       \
    u.d[0] = fh ? y1 : a01;  u.d[1] = fh ? y2 : a23;                      \
    u.d[2] = fh ? b01 : y1;  u.d[3] = fh ? b23 : y2;                      \
    *(f16x8*)(DST + (wid * 64 + 2 * ln31 + fh) * 8) = u.v; }

#define UP_STEP(R1, R3, BUF, KN_NEXT, ISSUE, VM)                               \
  { asm volatile("s_waitcnt vmcnt(" #VM ")" ::: "memory");                     \
    PACK1(R1, (&B1_lds[BUF][0]));                                              \
    PACK1(R3, (&B3_lds[BUF][0]));                                              \
    asm volatile("s_waitcnt lgkmcnt(0)" ::: "memory");                         \
    __builtin_amdgcn_s_barrier();                                              \
    asm volatile("" ::: "memory");                                             \
    if (ISSUE) { UP_ISSUE(R1, R3, KN_NEXT); }                                  \
    { f16x8 af[2][2], bf[2];                                                   \
      _Pragma("unroll") for (int mi = 0; mi < 2; ++mi)                         \
        _Pragma("unroll") for (int kk = 0; kk < 2; ++kk) {                     \
          int row = wr + mi * 32 + ln31;                                       \
          int cell = (kk * 2 + fh) ^ ((row >> 1) & 3);                         \
          af[mi][kk] = *(const f16x8*)&a_c[row * 32 + cell * 8]; }             \
      _Pragma("unroll") for (int kk = 0; kk < 2; ++kk)                         \
        bf[kk] = *(const f16x8*)(&B1_lds[BUF][0] + ((kk * 2 + fh) * 64 + wc + ln31) * 8); \
      __builtin_amdgcn_s_setprio(1);                                           \
      _Pragma("unroll") for (int kk = 0; kk < 2; ++kk)                         \
        _Pragma("unroll") for (int mi = 0; mi < 2; ++mi)                       \
          acc1[mi] = __builtin_amdgcn_mfma_f32_32x32x16_f16(af[mi][kk], bf[kk], acc1[mi], 0, 0, 0); \
      __builtin_amdgcn_s_setprio(0);                                           \
      _Pragma("unroll") for (int kk = 0; kk < 2; ++kk)                         \
        bf[kk] = *(const f16x8*)(&B3_lds[BUF][0] + ((kk * 2 + fh) * 64 + wc + ln31) * 8); \
      __builtin_amdgcn_s_setprio(1);                                           \
      _Pragma("unroll") for (int kk = 0; kk < 2; ++kk)                         \
        _Pragma("unroll") for (int mi = 0; mi < 2; ++mi)                       \
          acc3[mi] = __builtin_amdgcn_mfma_f32_32x32x16_f16(af[mi][kk], bf[kk], acc3[mi], 0, 0, 0); \
      __builtin_amdgcn_s_setprio(0); }                                         \
    ROT3(a_c, a_n, a_f); }

__launch_bounds__(256, 4)
__global__ void upproj_kernel(const f16* __restrict__ x16,
                              const float* __restrict__ w1,
                              const float* __restrict__ w3,
                              const int* __restrict__ counts,
                              const int* __restrict__ offsets,
                              const int* __restrict__ rows_perm,
                              f16* __restrict__ h_buf) {
  __shared__ __align__(16) f16 A_lds[3][BM * 32];
  __shared__ __align__(16) f16 B1_lds[2][4 * 64 * 8];
  __shared__ __align__(16) f16 B3_lds[2][4 * 64 * 8];

  int bid = blockIdx.x;
  int e = bid & 7;            // expert-locked XCD
  int slot = bid >> 3;        // 0..511
  int fidx = slot & 31;       // F/64
  int tile = slot >> 5;       // 0..15 -> capacity 2048 rows/expert
  int cnt = counts[e];
  if (tile * BM >= cnt) return;
  int row0 = tile * BM;
  int off = offsets[e];
  int f0 = fidx * 64;
  int t = threadIdx.x, wid = t >> 6, lane = t & 63;
  int ln31 = lane & 31, fh = lane >> 5;
  int wr = (wid >> 1) * 64, wc = (wid & 1) * 32;

  // A glds sources: 512 chunks (128 rows x 4 cells), 2/thread, swizzled cell
  const f16* asrc[2];
#pragma unroll
  for (int p = 0; p < 2; ++p) {
    int c = p * 256 + t;
    int row = c >> 2, cc = c & 3;
    int lr = row0 + row; if (lr > cnt - 1) lr = cnt - 1;
    asrc[p] = x16 + (size_t)rows_perm[off + lr] * C_DIM + 8 * (cc ^ ((row >> 1) & 3));
  }

  // B sources: row = k-window base (8*wid + 4*fh), col = f0 + 2*ln31
  const size_t eb = (size_t)e * C_DIM * F_DIM;
  const float* w1p = w1 + eb + (size_t)(8 * wid + 4 * fh) * F_DIM + f0 + 2 * ln31;
  const float* w3p = w3 + eb + (size_t)(8 * wid + 4 * fh) * F_DIM + f0 + 2 * ln31;

  f32x16 acc1[2] = {};
  f32x16 acc3[2] = {};
  f32x2 r1X[4], r3X[4], r1Y[4], r3Y[4];

  f16 *a_c = &A_lds[0][0], *a_n = &A_lds[1][0], *a_f = &A_lds[2][0];

  // prologue: set0 -> X banks/a_c, set1 -> Y banks/a_n
  { f16* sv = a_f; a_f = a_c; UP_ISSUE(r1X, r3X, 0); a_f = a_n; UP_ISSUE(r1Y, r3Y, 32); a_f = sv; }

  for (int tp = 0; tp < 15; ++tp) {
    UP_STEP(r1X, r3X, 0, (2 * tp + 2) * 32, 1, 10);
    UP_STEP(r1Y, r3Y, 1, (2 * tp + 3) * 32, 1, 10);
  }
  UP_STEP(r1X, r3X, 0, 0, 0, 10);
  UP_STEP(r1Y, r3Y, 1, 0, 0, 0);

#pragma unroll
  for (int mi = 0; mi < 2; ++mi)
#pragma unroll
    for (int i = 0; i < 16; ++i) {
      int rr = (i & 3) + 8 * (i >> 2) + 4 * fh;
      int lr = row0 + wr + mi * 32 + rr;
      if (lr < cnt) {
        float v1 = acc1[mi][i], v3 = acc3[mi][i];
        float hval = v1 / (1.f + expf(-v1)) * v3;
        h_buf[(size_t)(off + lr) * F_DIM + f0 + wc + ln31] = (f16)hval;
      }
    }
}

// ================= down-proj =================
#define DN_ISSUE(RB, KN)                                                  \
  { _Pragma("unroll") for (int j = 0; j < 4; ++j)                         \
      RB[j] = *(const f32x2*)(w2p + (size_t)((KN) + j) * C_DIM);          \
    glds16(asrc[0] + (KN), a_f + (wid * 64) * 8);                         \
    glds16(asrc[1] + (KN), a_f + (256 + wid * 64) * 8); }

#define DN_STEP(RB, BUF, KN_NEXT, ISSUE, VM)                                   \
  { asm volatile("s_waitcnt vmcnt(" #VM ")" ::: "memory");                     \
    PACK1(RB, (&B_lds[BUF][0]));                                               \
    asm volatile("s_waitcnt lgkmcnt(0)" ::: "memory");                         \
    __builtin_amdgcn_s_barrier();                                              \
    asm volatile("" ::: "memory");                                             \
    if (ISSUE) { DN_ISSUE(RB, KN_NEXT); }                                      \
    { f16x8 af[2][2], bf[2];                                                   \
      _Pragma("unroll") for (int mi = 0; mi < 2; ++mi)                         \
        _Pragma("unroll") for (int kk = 0; kk < 2; ++kk) {                     \
          int row = wr + mi * 32 + ln31;                                       \
          int cell = (kk * 2 + fh) ^ ((row >> 1) & 3);                         \
          af[mi][kk] = *(const f16x8*)&a_c[row * 32 + cell * 8]; }             \
      _Pragma("unroll") for (int kk = 0; kk < 2; ++kk)                         \
        bf[kk] = *(const f16x8*)(&B_lds[BUF][0] + ((kk * 2 + fh) * 64 + wc + ln31) * 8); \
      __builtin_amdgcn_s_setprio(1);                                           \
      _Pragma("unroll") for (int kk = 0; kk < 2; ++kk)                         \
        _Pragma("unroll") for (int mi = 0; mi < 2; ++mi)                       \
          acc[mi] = __builtin_amdgcn_mfma_f32_32x32x16_f16(af[mi][kk], bf[kk], acc[mi], 0, 0, 0); \
      __builtin_amdgcn_s_setprio(0); }                                         \
    ROT3(a_c, a_n, a_f); }

__launch_bounds__(256, 4)
__global__ void downproj_kernel(const f16* __restrict__ h_buf,
                                const float* __restrict__ w2,
                                const int* __restrict__ counts,
                                const int* __restrict__ offsets,
                                f16* __restrict__ y0,
                                f16* __restrict__ y1) {
  __shared__ __align__(16) f16 A_lds[3][BM * 32];
  __shared__ __align__(16) f16 B_lds[2][4 * 64 * 8];

  int bid = blockIdx.x;
  int e = bid & 7;
  int slot = bid >> 3;         // 0..511
  int cidx = slot & 15;        // C/64
  int kh = (slot >> 4) & 1;
  int tile = slot >> 5;        // 0..15 -> capacity 2048 rows/expert
  int cnt = counts[e];
  if (tile * BM >= cnt) return;
  f16* yb = kh ? y1 : y0;
  int row0 = tile * BM;
  int off = offsets[e];
  int c0 = cidx * 64;
  int t = threadIdx.x, wid = t >> 6, lane = t & 63;
  int ln31 = lane & 31, fh = lane >> 5;
  int wr = (wid >> 1) * 64, wc = (wid & 1) * 32;

  const f16* asrc[2];
#pragma unroll
  for (int p = 0; p < 2; ++p) {
    int c = p * 256 + t;
    int row = c >> 2, cc = c & 3;
    int lr = row0 + row; if (lr > cnt - 1) lr = cnt - 1;
    asrc[p] = h_buf + (size_t)(off + lr) * F_DIM + kh * 1024 + 8 * (cc ^ ((row >> 1) & 3));
  }

  const float* w2p = w2 + (size_t)e * F_DIM * C_DIM
                     + (size_t)(kh * 1024 + 8 * wid + 4 * fh) * C_DIM + c0 + 2 * ln31;

  f32x16 acc[2] = {};
  f32x2 rX[4], rY[4];

  f16 *a_c = &A_lds[0][0], *a_n = &A_lds[1][0], *a_f = &A_lds[2][0];

  { f16* sv = a_f; a_f = a_c; DN_ISSUE(rX, 0); a_f = a_n; DN_ISSUE(rY, 32); a_f = sv; }

  for (int tp = 0; tp < 15; ++tp) {
    DN_STEP(rX, 0, (2 * tp + 2) * 32, 1, 6);
    DN_STEP(rY, 1, (2 * tp + 3) * 32, 1, 6);
  }
  DN_STEP(rX, 0, 0, 0, 6);
  DN_STEP(rY, 1, 0, 0, 0);

#pragma unroll
  for (int mi = 0; mi < 2; ++mi)
#pragma unroll
    for (int i = 0; i < 16; ++i) {
      int rr = (i & 3) + 8 * (i >> 2) + 4 * fh;
      int lr = row0 + wr + mi * 32 + rr;
      if (lr < cnt)
        yb[(size_t)(off + lr) * C_DIM + c0 + wc + ln31] = (f16)acc[mi][i];
    }
}

// ---------------- combine ----------------
__global__ void combine_kernel(const f16* __restrict__ y0, const f16* __restrict__ y1,
                               const int* __restrict__ slot_of,
                               const float* __restrict__ topw,
                               float* __restrict__ out) {
  int n = blockIdx.x;
  int s0 = slot_of[2 * n], s1 = slot_of[2 * n + 1];
  float g0 = topw[2 * n], g1 = topw[2 * n + 1];
  int c = threadIdx.x * 4;
  f16x4 a0 = *(const f16x4*)(y0 + (size_t)s0 * C_DIM + c);
  f16x4 a1 = *(const f16x4*)(y1 + (size_t)s0 * C_DIM + c);
  f16x4 b0 = *(const f16x4*)(y0 + (size_t)s1 * C_DIM + c);
  f16x4 b1 = *(const f16x4*)(y1 + (size_t)s1 * C_DIM + c);
  f32x4 o;
#pragma unroll
  for (int i = 0; i < 4; ++i)
    o[i] = g0 * ((float)a0[i] + (float)a1[i]) + g1 * ((float)b0[i] + (float)b1[i]);
  *(f32x4*)(out + (size_t)n * C_DIM + c) = o;
}

extern "C" void kernel_launch(void* const* d_in, const int* in_sizes, int n_in,
                              void* d_out, int out_size, void* d_ws, size_t ws_size,
                              hipStream_t stream) {
  const float* x  = (const float*)d_in[0];
  const float* Wr = (const float*)d_in[1];
  const float* w1 = (const float*)d_in[2];
  const float* w3 = (const float*)d_in[3];
  const float* w2 = (const float*)d_in[4];
  float* out = (float*)d_out;
  char* ws = (char*)d_ws;

  int* counts    = (int*)(ws + WS_COUNTS);
  int* offsets   = (int*)(ws + WS_OFFSETS);
  int* cursor    = (int*)(ws + WS_CURSOR);
  int* topi      = (int*)(ws + WS_TOPI);
  float* topw    = (float*)(ws + WS_TOPW);
  int* rows_perm = (int*)(ws + WS_ROWS);
  int* slot_of   = (int*)(ws + WS_SLOT);
  f16* x16       = (f16*)(ws + WS_X16);
  f16* h_buf     = (f16*)(ws + WS_H);
  f16* y0        = (f16*)(ws + WS_Y0);
  f16* y1        = (f16*)(ws + WS_Y1);

  (void)hipMemsetAsync(ws, 0, 256, stream);
  cvtx_kernel<<<N_TOK * C_DIM / 8 / 256, 256, 0, stream>>>(x, x16);
  router_kernel<<<N_TOK / 4, 256, 0, stream>>>(x, Wr, counts, topi, topw);
  scan_kernel<<<1, 64, 0, stream>>>(counts, offsets, cursor);
  scatter_kernel<<<N_TOK / 256, 256, 0, stream>>>(topi, cursor, rows_perm, slot_of);
  upproj_kernel<<<E_NUM * 512, 256, 0, stream>>>(
      x16, w1, w3, counts, offsets, rows_perm, h_buf);
  downproj_kernel<<<E_NUM * 512, 256, 0, stream>>>(
      h_buf, w2, counts, offsets, y0, y1);
  combine_kernel<<<N_TOK, 256, 0, stream>>>(y0, y1, slot_of, topw, out);
}

// Round 13
// 232.200 us; speedup vs baseline: 2.1436x; 2.1436x over previous
//
#include <hip/hip_runtime.h>
#include <math.h>

typedef _Float16 f16;
typedef _Float16 f16x2 __attribute__((ext_vector_type(2)));
typedef _Float16 f16x4 __attribute__((ext_vector_type(4)));
typedef _Float16 f16x8 __attribute__((ext_vector_type(8)));
typedef __fp16 h16x2 __attribute__((ext_vector_type(2)));
typedef float f32x2 __attribute__((ext_vector_type(2)));
typedef float f32x4 __attribute__((ext_vector_type(4)));
typedef float f32x16 __attribute__((ext_vector_type(16)));

#define N_TOK 2048
#define C_DIM 1024
#define E_NUM 8
#define F_DIM 2048
#define BM 128

// ws layout (bytes)
#define WS_COUNTS    0
#define WS_OFFSETS   64
#define WS_CURSOR    192
#define WS_TOPI      256
#define WS_TOPW      (WS_TOPI + 16384)
#define WS_ROWS      (WS_TOPW + 16384)
#define WS_SLOT      (WS_ROWS + 16384)
#define WS_X16       (1ull << 20)     // 4 MB
#define WS_H         (6ull << 20)     // 16.8 MB
#define WS_Y0        (23ull << 20)    // 8.4 MB
#define WS_Y1        (32ull << 20)    // 8.4 MB

__device__ __forceinline__ void glds16(const void* g, void* l) {
  __builtin_amdgcn_global_load_lds((const __attribute__((address_space(1))) void*)g,
                                   (__attribute__((address_space(3))) void*)l, 16, 0, 0);
}

__device__ __forceinline__ f16x2 pkrtz(float a, float b) {
  union { h16x2 h; f16x2 f; } u;
  u.h = __builtin_amdgcn_cvt_pkrtz(a, b);
  return u.f;
}

__device__ __forceinline__ int f2i(f16x2 v) {
  union { f16x2 f; int i; } u; u.f = v; return u.i;
}

// ---------------- x fp32 -> fp16 ----------------
__global__ void cvtx_kernel(const float* __restrict__ x, f16* __restrict__ x16) {
  int i = (blockIdx.x * 256 + threadIdx.x) * 8;
  f32x4 a = *(const f32x4*)(x + i);
  f32x4 b = *(const f32x4*)(x + i + 4);
  union { f16x8 v; f16x2 h[4]; } u;
  u.h[0] = pkrtz(a[0], a[1]);
  u.h[1] = pkrtz(a[2], a[3]);
  u.h[2] = pkrtz(b[0], b[1]);
  u.h[3] = pkrtz(b[2], b[3]);
  *(f16x8*)(x16 + i) = u.v;
}

// ---------------- router ----------------
__global__ void router_kernel(const float* __restrict__ x, const float* __restrict__ Wr,
                              int* counts, int* topi, float* topw) {
  int tok = blockIdx.x * 4 + (threadIdx.x >> 6);
  int lane = threadIdx.x & 63;
  const float* xr = x + (size_t)tok * C_DIM;
  float xv[16];
#pragma unroll
  for (int i = 0; i < 16; ++i) xv[i] = xr[i * 64 + lane];
  float logit[E_NUM];
#pragma unroll
  for (int e = 0; e < E_NUM; ++e) {
    const float* wr = Wr + (size_t)e * C_DIM;
    float acc = 0.f;
#pragma unroll
    for (int i = 0; i < 16; ++i) acc += xv[i] * wr[i * 64 + lane];
#pragma unroll
    for (int s = 1; s < 64; s <<= 1) acc += __shfl_xor(acc, s, 64);
    logit[e] = acc;
  }
  if (lane == 0) {
    float m = logit[0];
#pragma unroll
    for (int e = 1; e < E_NUM; ++e) m = fmaxf(m, logit[e]);
    float p[E_NUM];
#pragma unroll
    for (int e = 0; e < E_NUM; ++e) p[e] = expf(logit[e] - m);
    float p0 = -1.f, p1 = -1.f;
    int i0 = 0, i1 = 0;
#pragma unroll
    for (int e = 0; e < E_NUM; ++e) {
      float v = p[e];
      if (v > p0) { p1 = p0; i1 = i0; p0 = v; i0 = e; }
      else if (v > p1) { p1 = v; i1 = e; }
    }
    float inv = 1.f / (p0 + p1);
    topi[2 * tok] = i0; topi[2 * tok + 1] = i1;
    topw[2 * tok] = p0 * inv; topw[2 * tok + 1] = p1 * inv;
    atomicAdd(&counts[i0], 1);
    atomicAdd(&counts[i1], 1);
  }
}

// ---------------- scan ----------------
__global__ void scan_kernel(const int* counts, int* offsets, int* cursor) {
  if (threadIdx.x == 0) {
    int o = 0;
    for (int e = 0; e < E_NUM; ++e) {
      offsets[e] = o; cursor[e] = o;
      o += counts[e];
    }
    offsets[E_NUM] = o;
  }
}

// ---------------- scatter ----------------
__global__ void scatter_kernel(const int* __restrict__ topi, int* cursor,
                               int* rows_perm, int* slot_of) {
  int n = blockIdx.x * blockDim.x + threadIdx.x;
  if (n >= N_TOK) return;
#pragma unroll
  for (int k = 0; k < 2; ++k) {
    int e = topi[2 * n + k];
    int pos = atomicAdd(&cursor[e], 1);
    rows_perm[pos] = n;
    slot_of[2 * n + k] = pos;
  }
}

#define ROT3(P0, P1, P2) { f16* _t = P0; P0 = P1; P1 = P2; P2 = _t; }

// ================= up-proj: h = silu(x@w1)*(x@w3) =================
// 128x64 tile, BK=32, 4 waves (wave 64x32), 32x32x16 MFMA, 3 blocks/CU.
// A: glds (swizzled src, 3-buf, depth-2). B: coalesced dwordx2 fp32 loads
// + pkrtz + shfl_xor(32) col-exchange -> thread-linear ds_write_b128.
// Thread t: col pair c0=2*(lane&31), k-window = 8*wid + 4*fh (4 rows).
#define UP_ISSUE(R1, R3, KN)                                              \
  { _Pragma("unroll") for (int j = 0; j < 4; ++j) {                       \
      R1[j] = *(const f32x2*)(w1p + (size_t)((KN) + j) * F_DIM);          \
      R3[j] = *(const f32x2*)(w3p + (size_t)((KN) + j) * F_DIM); }        \
    glds16(asrc[0] + (KN), a_f + (wid * 64) * 8);                         \
    glds16(asrc[1] + (KN), a_f + (256 + wid * 64) * 8); }

#define PACK1(R, DST)                                                     \
  { int a01 = f2i(pkrtz(R[0][0], R[1][0]));                               \
    int a23 = f2i(pkrtz(R[2][0], R[3][0]));                               \
    int b01 = f2i(pkrtz(R[0][1], R[1][1]));                               \
    int b23 = f2i(pkrtz(R[2][1], R[3][1]));                               \
    int x1 = fh ? a01 : b01;     /* send the col you don't own */         \
    int x2 = fh ? a23 : b23;                                              \
    int y1 = __shfl_xor(x1, 32, 64);                                      \
    int y2 = __shfl_xor(x2, 32, 64);                                      \
    union { f16x8 v; int d[4]; } u;                                       \
    u.d[0] = fh ? y1 : a01;  u.d[1] = fh ? y2 : a23;                      \
    u.d[2] = fh ? b01 : y1;  u.d[3] = fh ? b23 : y2;                      \
    *(f16x8*)(DST + (wid * 64 + 2 * ln31 + fh) * 8) = u.v; }

#define UP_STEP(R1, R3, BUF, KN_NEXT, ISSUE, VM)                               \
  { asm volatile("s_waitcnt vmcnt(" #VM ")" ::: "memory");                     \
    PACK1(R1, (&B1_lds[BUF][0]));                                              \
    PACK1(R3, (&B3_lds[BUF][0]));                                              \
    asm volatile("s_waitcnt lgkmcnt(0)" ::: "memory");                         \
    __builtin_amdgcn_s_barrier();                                              \
    asm volatile("" ::: "memory");                                             \
    if (ISSUE) { UP_ISSUE(R1, R3, KN_NEXT); }                                  \
    { f16x8 af[2][2], bf[2];                                                   \
      _Pragma("unroll") for (int mi = 0; mi < 2; ++mi)                         \
        _Pragma("unroll") for (int kk = 0; kk < 2; ++kk) {                     \
          int row = wr + mi * 32 + ln31;                                       \
          int cell = (kk * 2 + fh) ^ ((row >> 1) & 3);                         \
          af[mi][kk] = *(const f16x8*)&a_c[row * 32 + cell * 8]; }             \
      _Pragma("unroll") for (int kk = 0; kk < 2; ++kk)                         \
        bf[kk] = *(const f16x8*)(&B1_lds[BUF][0] + ((kk * 2 + fh) * 64 + wc + ln31) * 8); \
      __builtin_amdgcn_s_setprio(1);                                           \
      _Pragma("unroll") for (int kk = 0; kk < 2; ++kk)                         \
        _Pragma("unroll") for (int mi = 0; mi < 2; ++mi)                       \
          acc1[mi] = __builtin_amdgcn_mfma_f32_32x32x16_f16(af[mi][kk], bf[kk], acc1[mi], 0, 0, 0); \
      __builtin_amdgcn_s_setprio(0);                                           \
      _Pragma("unroll") for (int kk = 0; kk < 2; ++kk)                         \
        bf[kk] = *(const f16x8*)(&B3_lds[BUF][0] + ((kk * 2 + fh) * 64 + wc + ln31) * 8); \
      __builtin_amdgcn_s_setprio(1);                                           \
      _Pragma("unroll") for (int kk = 0; kk < 2; ++kk)                         \
        _Pragma("unroll") for (int mi = 0; mi < 2; ++mi)                       \
          acc3[mi] = __builtin_amdgcn_mfma_f32_32x32x16_f16(af[mi][kk], bf[kk], acc3[mi], 0, 0, 0); \
      __builtin_amdgcn_s_setprio(0); }                                         \
    ROT3(a_c, a_n, a_f); }

__launch_bounds__(256, 3)
__global__ void upproj_kernel(const f16* __restrict__ x16,
                              const float* __restrict__ w1,
                              const float* __restrict__ w3,
                              const int* __restrict__ counts,
                              const int* __restrict__ offsets,
                              const int* __restrict__ rows_perm,
                              f16* __restrict__ h_buf) {
  __shared__ __align__(16) f16 A_lds[3][BM * 32];
  __shared__ __align__(16) f16 B1_lds[2][4 * 64 * 8];
  __shared__ __align__(16) f16 B3_lds[2][4 * 64 * 8];

  int bid = blockIdx.x;
  int e = bid & 7;            // expert-locked XCD
  int slot = bid >> 3;        // 0..511
  int fidx = slot & 31;       // F/64
  int tile = slot >> 5;       // 0..15 -> capacity 2048 rows/expert
  int cnt = counts[e];
  if (tile * BM >= cnt) return;
  int row0 = tile * BM;
  int off = offsets[e];
  int f0 = fidx * 64;
  int t = threadIdx.x, wid = t >> 6, lane = t & 63;
  int ln31 = lane & 31, fh = lane >> 5;
  int wr = (wid >> 1) * 64, wc = (wid & 1) * 32;

  // A glds sources: 512 chunks (128 rows x 4 cells), 2/thread, swizzled cell
  const f16* asrc[2];
#pragma unroll
  for (int p = 0; p < 2; ++p) {
    int c = p * 256 + t;
    int row = c >> 2, cc = c & 3;
    int lr = row0 + row; if (lr > cnt - 1) lr = cnt - 1;
    asrc[p] = x16 + (size_t)rows_perm[off + lr] * C_DIM + 8 * (cc ^ ((row >> 1) & 3));
  }

  // B sources: row = k-window base (8*wid + 4*fh), col = f0 + 2*ln31
  const size_t eb = (size_t)e * C_DIM * F_DIM;
  const float* w1p = w1 + eb + (size_t)(8 * wid + 4 * fh) * F_DIM + f0 + 2 * ln31;
  const float* w3p = w3 + eb + (size_t)(8 * wid + 4 * fh) * F_DIM + f0 + 2 * ln31;

  f32x16 acc1[2] = {};
  f32x16 acc3[2] = {};
  f32x2 r1X[4], r3X[4], r1Y[4], r3Y[4];

  f16 *a_c = &A_lds[0][0], *a_n = &A_lds[1][0], *a_f = &A_lds[2][0];

  // prologue: set0 -> X banks/a_c, set1 -> Y banks/a_n
  { f16* sv = a_f; a_f = a_c; UP_ISSUE(r1X, r3X, 0); a_f = a_n; UP_ISSUE(r1Y, r3Y, 32); a_f = sv; }

  for (int tp = 0; tp < 15; ++tp) {
    UP_STEP(r1X, r3X, 0, (2 * tp + 2) * 32, 1, 10);
    UP_STEP(r1Y, r3Y, 1, (2 * tp + 3) * 32, 1, 10);
  }
  UP_STEP(r1X, r3X, 0, 0, 0, 10);
  UP_STEP(r1Y, r3Y, 1, 0, 0, 0);

#pragma unroll
  for (int mi = 0; mi < 2; ++mi)
#pragma unroll
    for (int i = 0; i < 16; ++i) {
      int rr = (i & 3) + 8 * (i >> 2) + 4 * fh;
      int lr = row0 + wr + mi * 32 + rr;
      if (lr < cnt) {
        float v1 = acc1[mi][i], v3 = acc3[mi][i];
        float hval = v1 / (1.f + expf(-v1)) * v3;
        h_buf[(size_t)(off + lr) * F_DIM + f0 + wc + ln31] = (f16)hval;
      }
    }
}

// ================= down-proj =================
#define DN_ISSUE(RB, KN)                                                  \
  { _Pragma("unroll") for (int j = 0; j < 4; ++j)                         \
      RB[j] = *(const f32x2*)(w2p + (size_t)((KN) + j) * C_DIM);          \
    glds16(asrc[0] + (KN), a_f + (wid * 64) * 8);                         \
    glds16(asrc[1] + (KN), a_f + (256 + wid * 64) * 8); }

#define DN_STEP(RB, BUF, KN_NEXT, ISSUE, VM)                                   \
  { asm volatile("s_waitcnt vmcnt(" #VM ")" ::: "memory");                     \
    PACK1(RB, (&B_lds[BUF][0]));                                               \
    asm volatile("s_waitcnt lgkmcnt(0)" ::: "memory");                         \
    __builtin_amdgcn_s_barrier();                                              \
    asm volatile("" ::: "memory");                                             \
    if (ISSUE) { DN_ISSUE(RB, KN_NEXT); }                                      \
    { f16x8 af[2][2], bf[2];                                                   \
      _Pragma("unroll") for (int mi = 0; mi < 2; ++mi)                         \
        _Pragma("unroll") for (int kk = 0; kk < 2; ++kk) {                     \
          int row = wr + mi * 32 + ln31;                                       \
          int cell = (kk * 2 + fh) ^ ((row >> 1) & 3);                         \
          af[mi][kk] = *(const f16x8*)&a_c[row * 32 + cell * 8]; }             \
      _Pragma("unroll") for (int kk = 0; kk < 2; ++kk)                         \
        bf[kk] = *(const f16x8*)(&B_lds[BUF][0] + ((kk * 2 + fh) * 64 + wc + ln31) * 8); \
      __builtin_amdgcn_s_setprio(1);                                           \
      _Pragma("unroll") for (int kk = 0; kk < 2; ++kk)                         \
        _Pragma("unroll") for (int mi = 0; mi < 2; ++mi)                       \
          acc[mi] = __builtin_amdgcn_mfma_f32_32x32x16_f16(af[mi][kk], bf[kk], acc[mi], 0, 0, 0); \
      __builtin_amdgcn_s_setprio(0); }                                         \
    ROT3(a_c, a_n, a_f); }

__launch_bounds__(256, 3)
__global__ void downproj_kernel(const f16* __restrict__ h_buf,
                                const float* __restrict__ w2,
                                const int* __restrict__ counts,
                                const int* __restrict__ offsets,
                                f16* __restrict__ y0,
                                f16* __restrict__ y1) {
  __shared__ __align__(16) f16 A_lds[3][BM * 32];
  __shared__ __align__(16) f16 B_lds[2][4 * 64 * 8];

  int bid = blockIdx.x;
  int e = bid & 7;
  int slot = bid >> 3;         // 0..511
  int cidx = slot & 15;        // C/64
  int kh = (slot >> 4) & 1;
  int tile = slot >> 5;        // 0..15 -> capacity 2048 rows/expert
  int cnt = counts[e];
  if (tile * BM >= cnt) return;
  f16* yb = kh ? y1 : y0;
  int row0 = tile * BM;
  int off = offsets[e];
  int c0 = cidx * 64;
  int t = threadIdx.x, wid = t >> 6, lane = t & 63;
  int ln31 = lane & 31, fh = lane >> 5;
  int wr = (wid >> 1) * 64, wc = (wid & 1) * 32;

  const f16* asrc[2];
#pragma unroll
  for (int p = 0; p < 2; ++p) {
    int c = p * 256 + t;
    int row = c >> 2, cc = c & 3;
    int lr = row0 + row; if (lr > cnt - 1) lr = cnt - 1;
    asrc[p] = h_buf + (size_t)(off + lr) * F_DIM + kh * 1024 + 8 * (cc ^ ((row >> 1) & 3));
  }

  const float* w2p = w2 + (size_t)e * F_DIM * C_DIM
                     + (size_t)(kh * 1024 + 8 * wid + 4 * fh) * C_DIM + c0 + 2 * ln31;

  f32x16 acc[2] = {};
  f32x2 rX[4], rY[4];

  f16 *a_c = &A_lds[0][0], *a_n = &A_lds[1][0], *a_f = &A_lds[2][0];

  { f16* sv = a_f; a_f = a_c; DN_ISSUE(rX, 0); a_f = a_n; DN_ISSUE(rY, 32); a_f = sv; }

  for (int tp = 0; tp < 15; ++tp) {
    DN_STEP(rX, 0, (2 * tp + 2) * 32, 1, 6);
    DN_STEP(rY, 1, (2 * tp + 3) * 32, 1, 6);
  }
  DN_STEP(rX, 0, 0, 0, 6);
  DN_STEP(rY, 1, 0, 0, 0);

#pragma unroll
  for (int mi = 0; mi < 2; ++mi)
#pragma unroll
    for (int i = 0; i < 16; ++i) {
      int rr = (i & 3) + 8 * (i >> 2) + 4 * fh;
      int lr = row0 + wr + mi * 32 + rr;
      if (lr < cnt)
        yb[(size_t)(off + lr) * C_DIM + c0 + wc + ln31] = (f16)acc[mi][i];
    }
}

// ---------------- combine ----------------
__global__ void combine_kernel(const f16* __restrict__ y0, const f16* __restrict__ y1,
                               const int* __restrict__ slot_of,
                               const float* __restrict__ topw,
                               float* __restrict__ out) {
  int n = blockIdx.x;
  int s0 = slot_of[2 * n], s1 = slot_of[2 * n + 1];
  float g0 = topw[2 * n], g1 = topw[2 * n + 1];
  int c = threadIdx.x * 4;
  f16x4 a0 = *(const f16x4*)(y0 + (size_t)s0 * C_DIM + c);
  f16x4 a1 = *(const f16x4*)(y1 + (size_t)s0 * C_DIM + c);
  f16x4 b0 = *(const f16x4*)(y0 + (size_t)s1 * C_DIM + c);
  f16x4 b1 = *(const f16x4*)(y1 + (size_t)s1 * C_DIM + c);
  f32x4 o;
#pragma unroll
  for (int i = 0; i < 4; ++i)
    o[i] = g0 * ((float)a0[i] + (float)a1[i]) + g1 * ((float)b0[i] + (float)b1[i]);
  *(f32x4*)(out + (size_t)n * C_DIM + c) = o;
}

extern "C" void kernel_launch(void* const* d_in, const int* in_sizes, int n_in,
                              void* d_out, int out_size, void* d_ws, size_t ws_size,
                              hipStream_t stream) {
  const float* x  = (const float*)d_in[0];
  const float* Wr = (const float*)d_in[1];
  const float* w1 = (const float*)d_in[2];
  const float* w3 = (const float*)d_in[3];
  const float* w2 = (const float*)d_in[4];
  float* out = (float*)d_out;
  char* ws = (char*)d_ws;

  int* counts    = (int*)(ws + WS_COUNTS);
  int* offsets   = (int*)(ws + WS_OFFSETS);
  int* cursor    = (int*)(ws + WS_CURSOR);
  int* topi      = (int*)(ws + WS_TOPI);
  float* topw    = (float*)(ws + WS_TOPW);
  int* rows_perm = (int*)(ws + WS_ROWS);
  int* slot_of   = (int*)(ws + WS_SLOT);
  f16* x16       = (f16*)(ws + WS_X16);
  f16* h_buf     = (f16*)(ws + WS_H);
  f16* y0        = (f16*)(ws + WS_Y0);
  f16* y1        = (f16*)(ws + WS_Y1);

  (void)hipMemsetAsync(ws, 0, 256, stream);
  cvtx_kernel<<<N_TOK * C_DIM / 8 / 256, 256, 0, stream>>>(x, x16);
  router_kernel<<<N_TOK / 4, 256, 0, stream>>>(x, Wr, counts, topi, topw);
  scan_kernel<<<1, 64, 0, stream>>>(counts, offsets, cursor);
  scatter_kernel<<<N_TOK / 256, 256, 0, stream>>>(topi, cursor, rows_perm, slot_of);
  upproj_kernel<<<E_NUM * 512, 256, 0, stream>>>(
      x16, w1, w3, counts, offsets, rows_perm, h_buf);
  downproj_kernel<<<E_NUM * 512, 256, 0, stream>>>(
      h_buf, w2, counts, offsets, y0, y1);
  combine_kernel<<<N_TOK, 256, 0, stream>>>(y0, y1, slot_of, topw, out);
}